// Round 12
// baseline (219.265 us; speedup 1.0000x reference)
//
#include <hip/hip_runtime.h>

#define D_ 256
#define DH_ 128
#define NBMAX 128
#define BCAP 9216

using bf16x8 = __attribute__((ext_vector_type(8))) short;
using f32x4  = __attribute__((ext_vector_type(4))) float;
using f32x2  = __attribute__((ext_vector_type(2))) float;

__device__ __forceinline__ unsigned short f2bf(float f) {
  unsigned int u = __builtin_bit_cast(unsigned int, f);
  u += 0x7fffu + ((u >> 16) & 1u);
  return (unsigned short)(u >> 16);
}
__device__ __forceinline__ unsigned char f2fp8(float f) {
  unsigned int pk = __builtin_amdgcn_cvt_pk_fp8_f32(f, 0.f, 0u, false);
  return (unsigned char)(pk & 0xffu);
}

// ---------------- bucketed CSR build ----------------
// Edges pack into u32 (src | dst<<16) since N < 65536. Buckets of 512 dst nodes.
// part_k: per-wave histograms + int4-vectorized edge loads (16 edges/thread).

__global__ __launch_bounds__(512) void part_k(const int* __restrict__ fw,
                                              const int* __restrict__ bw,
                                              int* __restrict__ gcnt,
                                              unsigned int* __restrict__ buckets,
                                              int E_, int nb) {
  __shared__ int hist[8][NBMAX];   // per-wave histograms (4 KiB)
  int g = blockIdx.y;
  const int* src = (g < 2 ? fw : bw) + (size_t)(g & 1) * 2 * E_;
  const int* dst = src + E_;
  int t = threadIdx.x, w = t >> 6;
  for (int i = t; i < 8 * NBMAX; i += 512) ((int*)hist)[i] = 0;
  __syncthreads();
  int base = blockIdx.x * 8192 + t * 16;   // 16 contiguous edges per thread
  unsigned int pk[16];
  int lp[16];
  if (base + 16 <= E_) {
#pragma unroll
    for (int q = 0; q < 4; ++q) {
      int4 sv = *(const int4*)(src + base + q * 4);
      int4 dv = *(const int4*)(dst + base + q * 4);
      int ss[4] = {sv.x, sv.y, sv.z, sv.w};
      int dd[4] = {dv.x, dv.y, dv.z, dv.w};
#pragma unroll
      for (int r = 0; r < 4; ++r) {
        int j = q * 4 + r;
        pk[j] = (unsigned int)ss[r] | ((unsigned int)dd[r] << 16);
        lp[j] = atomicAdd(&hist[w][dd[r] >> 9], 1);
      }
    }
  } else {
#pragma unroll
    for (int j = 0; j < 16; ++j) {
      int e = base + j;
      if (e < E_) {
        int s = src[e], d = dst[e];
        pk[j] = (unsigned int)s | ((unsigned int)d << 16);
        lp[j] = atomicAdd(&hist[w][d >> 9], 1);
      } else {
        pk[j] = 0u; lp[j] = -1;
      }
    }
  }
  __syncthreads();
  // per-bucket: reserve global range once, convert per-wave hist into running bases
  if (t < nb) {
    int tot = 0;
#pragma unroll
    for (int ww = 0; ww < 8; ++ww) tot += hist[ww][t];
    int gb = atomicAdd(&gcnt[g * NBMAX + t], tot);
    int run = gb;
#pragma unroll
    for (int ww = 0; ww < 8; ++ww) { int h = hist[ww][t]; hist[ww][t] = run; run += h; }
  }
  __syncthreads();
#pragma unroll
  for (int j = 0; j < 16; ++j) {
    if (lp[j] >= 0) {
      int b = pk[j] >> 25;  // dst >> 9
      int pos = hist[w][b] + lp[j];
      if (pos < BCAP) buckets[((size_t)(g * NBMAX + b)) * BCAP + pos] = pk[j];
    }
  }
}

__global__ __launch_bounds__(512) void csr_k(const unsigned int* __restrict__ buckets,
                                             const int* __restrict__ gcnt,
                                             int* __restrict__ deg, int* __restrict__ offs,
                                             int* __restrict__ csr, int N_, int E_) {
  __shared__ int ldeg[512];
  __shared__ int loff[512];
  __shared__ int wsum[8];
  __shared__ int red[8];
  int g = blockIdx.y, b = blockIdx.x;
  int t = threadIdx.x;
  int lane = t & 63, w = t >> 6;
  int cnt = min(gcnt[g * NBMAX + b], BCAP);
  const unsigned int* ebuf = buckets + ((size_t)(g * NBMAX + b)) * BCAP;
  int nodebase = b << 9;
  int nloc = min(512, N_ - nodebase);
  ldeg[t] = 0;
  // inline bucket-base prefix: gb = sum_{j<b} min(gcnt[g][j], BCAP)
  int val = (t < b) ? min(gcnt[g * NBMAX + t], BCAP) : 0;
  for (int o = 1; o < 64; o <<= 1) val += __shfl_xor(val, o, 64);
  if (lane == 0) red[w] = val;
  __syncthreads();
  int gb = 0;
#pragma unroll
  for (int k = 0; k < 8; ++k) gb += red[k];
  for (int i = t; i < cnt; i += 512) atomicAdd(&ldeg[(ebuf[i] >> 16) & 511], 1);
  __syncthreads();
  // exclusive scan of 512 counts: 8 waves x 64 (1/lane)
  int a0 = ldeg[t];
  int incl = a0;
  for (int o = 1; o < 64; o <<= 1) {
    int x = __shfl_up(incl, o, 64);
    if (lane >= o) incl += x;
  }
  if (lane == 63) wsum[w] = incl;
  __syncthreads();
  int wpre = 0;
  for (int k = 0; k < w; ++k) wpre += wsum[k];
  loff[t] = wpre + incl - a0;
  __syncthreads();
  if (t < nloc) {
    deg[(size_t)g * N_ + nodebase + t] = ldeg[t];
    offs[(size_t)g * N_ + nodebase + t] = gb + loff[t];
  }
  ldeg[t] = 0;
  __syncthreads();
  int* csrg = csr + (size_t)g * E_ + gb;
  for (int i = t; i < cnt; i += 512) {
    unsigned int pk = ebuf[i];
    int d = (pk >> 16) & 511;
    int lp = atomicAdd(&ldeg[d], 1);
    csrg[loff[d] + lp] = (int)(pk & 0xffffu);
  }
}

// ---------------- weight prep: transposed bf16 weights (+ gcnt zeroing) ----------------

__global__ void prepw_k(const float* __restrict__ Wfw, const float* __restrict__ Wbw,
                        const float* __restrict__ W1,
                        unsigned short* __restrict__ Wt, unsigned short* __restrict__ W1t,
                        int* __restrict__ gcnt) {
  int i = blockIdx.x * blockDim.x + threadIdx.x;
  if (i < 4 * NBMAX) gcnt[i] = 0;
  const int nw = 4 * D_ * DH_;  // 131072
  if (i < nw) {
    int g = i >> 15;
    int r = i & 32767;
    int n = r >> 8, k = r & 255; // Wt[g][n][k] (DHxD, k contiguous)
    const float* W = (g < 2 ? Wfw : Wbw) + (size_t)(g & 1) * D_ * DH_;
    Wt[i] = f2bf(W[k * DH_ + n]);
  } else if (i < nw + D_ * D_) {
    int r = i - nw;
    int c = r >> 8, k = r & 255; // W1t[c][k]
    W1t[r] = f2bf(W1[k * D_ + c]);
  }
}

// ---------------- y_g = x @ W_g, 64-row tiles, 8 waves (wave -> graph/col-half) ----------------

__global__ __launch_bounds__(512, 4) void ygemm_k(const float* __restrict__ x,
                                                  const unsigned short* __restrict__ Wt,
                                                  unsigned char* __restrict__ y, int N_) {
  __shared__ unsigned short At[64 * 256];  // 32 KiB XOR-swizzled bf16 tile of x
  int t = threadIdx.x, lane = t & 63, w = t >> 6;
  int tile = blockIdx.x;
#pragma unroll
  for (int it = 0; it < 8; ++it) {
    int idx = it * 512 + t;          // 4096 float4 slots = 64 rows x 64
    int row = idx >> 6, slot = idx & 63;
    int gr = tile * 64 + row;
    float4 v = {0.f, 0.f, 0.f, 0.f};
    if (gr < N_) v = ((const float4*)x)[(size_t)gr * 64 + slot];
    int c = slot * 4;
    int sc2 = (c & 7) | ((((c >> 3)) ^ (row & 7)) << 3);
    ushort4 o;
    o.x = f2bf(v.x); o.y = f2bf(v.y); o.z = f2bf(v.z); o.w = f2bf(v.w);
    *(ushort4*)&At[row * 256 + sc2] = o;
  }
  __syncthreads();
  int krow = (lane >> 4) * 8;
  int l15 = lane & 15;
  int g = w >> 1, ch = w & 1;      // wave -> (graph, column half)
  const unsigned short* Wg = Wt + (size_t)g * (DH_ * D_);
  f32x4 acc[4][4];
#pragma unroll
  for (int a = 0; a < 4; ++a)
#pragma unroll
    for (int b = 0; b < 4; ++b) acc[a][b] = (f32x4){0.f, 0.f, 0.f, 0.f};
#pragma unroll
  for (int kk = 0; kk < 8; ++kk) {
    bf16x8 bfr[4];
#pragma unroll
    for (int ct = 0; ct < 4; ++ct) {
      int n = ch * 64 + ct * 16 + l15;
      bfr[ct] = *(const bf16x8*)(Wg + (size_t)n * 256 + kk * 32 + krow);
    }
    bf16x8 afr[4];
#pragma unroll
    for (int rt = 0; rt < 4; ++rt) {
      int r = rt * 16 + l15;
      int cc = kk * 32 + krow;
      afr[rt] = *(const bf16x8*)&At[r * 256 + (cc ^ ((r & 7) << 3))];
    }
#pragma unroll
    for (int ct = 0; ct < 4; ++ct)
#pragma unroll
      for (int rt = 0; rt < 4; ++rt)
        acc[rt][ct] = __builtin_amdgcn_mfma_f32_16x16x32_bf16(afr[rt], bfr[ct], acc[rt][ct], 0, 0, 0);
  }
  unsigned char* yg = y + (size_t)g * N_ * DH_;
#pragma unroll
  for (int rt = 0; rt < 4; ++rt)
#pragma unroll
    for (int j = 0; j < 4; ++j) {
      int row = tile * 64 + rt * 16 + (lane >> 4) * 4 + j;
      if (row < N_) {
#pragma unroll
        for (int ct = 0; ct < 4; ++ct)
          yg[(size_t)row * DH_ + ch * 64 + ct * 16 + l15] = f2fp8(acc[rt][ct][j]);
      }
    }
}

// ---------------- gather: 16-lane group per row, no cross-lane reduction ----------------

__device__ __forceinline__ void acc2(f32x2* s, uint2 q) {
  s[0] += __builtin_amdgcn_cvt_pk_f32_fp8(q.x, false);
  s[1] += __builtin_amdgcn_cvt_pk_f32_fp8(q.x, true);
  s[2] += __builtin_amdgcn_cvt_pk_f32_fp8(q.y, false);
  s[3] += __builtin_amdgcn_cvt_pk_f32_fp8(q.y, true);
}

#define GATHER(sacc, dgv, offv, gidx)                                                   \
  {                                                                                     \
    const int* lst = csr + (size_t)(gidx) * E_ + (offv);                                \
    const unsigned char* yg = y + (size_t)(gidx) * N_ * DH_;                            \
    int jend = (dgv) & ~3;                                                              \
    int j = 0;                                                                          \
    _Pragma("unroll 1")                                                                 \
    for (; j < jend; j += 4) {                                                          \
      int4 iv = *(const int4*)(lst + j);                                                \
      uint2 q0 = *(const uint2*)(yg + ((((unsigned)iv.x & 0xffffu) << 7) + boff));      \
      uint2 q1 = *(const uint2*)(yg + ((((unsigned)iv.y & 0xffffu) << 7) + boff));      \
      uint2 q2 = *(const uint2*)(yg + ((((unsigned)iv.z & 0xffffu) << 7) + boff));      \
      uint2 q3 = *(const uint2*)(yg + ((((unsigned)iv.w & 0xffffu) << 7) + boff));      \
      acc2(sacc, q0); acc2(sacc, q1); acc2(sacc, q2); acc2(sacc, q3);                   \
    }                                                                                   \
    if (j < (dgv)) {                                                                    \
      int4 iv = *(const int4*)(lst + j);                                                \
      uint2 q0 = *(const uint2*)(yg + ((((unsigned)iv.x & 0xffffu) << 7) + boff));      \
      uint2 q1 = *(const uint2*)(yg + ((((unsigned)iv.y & 0xffffu) << 7) + boff));      \
      uint2 q2 = *(const uint2*)(yg + ((((unsigned)iv.z & 0xffffu) << 7) + boff));      \
      if (j + 0 < (dgv)) acc2(sacc, q0);                                                \
      if (j + 1 < (dgv)) acc2(sacc, q1);                                                \
      if (j + 2 < (dgv)) acc2(sacc, q2);                                                \
    }                                                                                   \
  }

__global__ __launch_bounds__(256, 6) void gnn2_k(
    const unsigned char* __restrict__ y,
    const int* __restrict__ deg, const int* __restrict__ offs, const int* __restrict__ csr,
    const float* __restrict__ bias_fw, const float* __restrict__ bias_bw,
    unsigned short* __restrict__ accb, int N_, int E_) {
  const int tid = threadIdx.x;
  const int lane = tid & 63, w = tid >> 6;
  const int grp = lane >> 4, l15 = lane & 15;
  const int tile = blockIdx.x, dir = blockIdx.y;  // 0 = fw, 1 = bw
  const int colbase = dir ? 0 : 128;              // concat([bw, fw])
  const float* bias = dir ? bias_bw : bias_fw;
  const unsigned boff = l15 * 8;  // byte (and element) offset within the 128-B fp8 row
  const int g0 = dir * 2, g1 = g0 + 1;

  // prefetch metadata for both rows this group owns
  int dgP[2][2], offP[2][2];
#pragma unroll
  for (int rr = 0; rr < 2; ++rr) {
    int nd = tile * 32 + rr * 16 + w * 4 + grp;
    bool act = nd < N_;
    int nds = act ? nd : 0;
    dgP[rr][0] = act ? deg[(size_t)g0 * N_ + nds] : 0;
    offP[rr][0] = offs[(size_t)g0 * N_ + nds];
    dgP[rr][1] = act ? deg[(size_t)g1 * N_ + nds] : 0;
    offP[rr][1] = offs[(size_t)g1 * N_ + nds];
  }

#pragma unroll 1
  for (int rr = 0; rr < 2; ++rr) {
    int nd = tile * 32 + rr * 16 + w * 4 + grp;   // this group's row
    bool act = nd < N_;
    f32x2 s0[4], s1[4];
#pragma unroll
    for (int k = 0; k < 4; ++k) { s0[k] = (f32x2){0.f, 0.f}; s1[k] = (f32x2){0.f, 0.f}; }
    int dg0 = dgP[rr][0], off0 = offP[rr][0];
    int dg1 = dgP[rr][1], off1 = offP[rr][1];

    GATHER(s0, dg0, off0, g0);
    GATHER(s1, dg1, off1, g1);

    float sc0 = 1.0f / (float)max(dg0, 1);
    float sc1 = 1.0f / (float)max(dg1, 1);
    const float* bp0 = bias + boff;
    const float* bp1 = bias + DH_ + boff;
    uint4 pk;
    unsigned* pw = (unsigned*)&pk;
#pragma unroll
    for (int k = 0; k < 4; ++k) {
      float h0 = fmaxf(s0[k].x * sc0 + bp0[2 * k],     0.f) + fmaxf(s1[k].x * sc1 + bp1[2 * k],     0.f);
      float h1 = fmaxf(s0[k].y * sc0 + bp0[2 * k + 1], 0.f) + fmaxf(s1[k].y * sc1 + bp1[2 * k + 1], 0.f);
      pw[k] = (unsigned)f2bf(h0) | ((unsigned)f2bf(h1) << 16);
    }
    if (act) *(uint4*)(accb + (size_t)nd * 256 + colbase + boff) = pk;
  }
}

// ---------------- GEMM2: out = accb @ W1 + b1 + inps (64-row tiles, 8 waves) ----------------

__global__ __launch_bounds__(512, 4) void gemm2_k(
    const unsigned short* __restrict__ accb, const unsigned short* __restrict__ W1t,
    const float* __restrict__ b1, const float* __restrict__ x,
    float* __restrict__ out, int N_) {
  __shared__ unsigned short Bt[64 * 256];  // 32 KiB XOR-swizzled accb tile
  int tid = threadIdx.x;
  int lane = tid & 63, w = tid >> 6;
  int l15 = lane & 15;
  int tile = blockIdx.x;
  // stage: 2048 x 16B slots, coalesced (32 consecutive slots per row)
#pragma unroll
  for (int it = 0; it < 4; ++it) {
    int idx = it * 512 + tid;
    int row = idx >> 5, slot = idx & 31;
    int gr = min(tile * 64 + row, N_ - 1);
    uint4 v = *(const uint4*)(accb + (size_t)gr * 256 + slot * 8);
    int c = slot * 8;
    *(uint4*)&Bt[row * 256 + (c ^ ((row & 7) << 3))] = v;
  }
  __syncthreads();
  f32x4 acc[4][2];
#pragma unroll
  for (int a = 0; a < 4; ++a)
#pragma unroll
    for (int b = 0; b < 2; ++b) acc[a][b] = (f32x4){0.f, 0.f, 0.f, 0.f};
  int krow = (lane >> 4) * 8;
#pragma unroll
  for (int kk = 0; kk < 8; ++kk) {
    bf16x8 bfr[2];
#pragma unroll
    for (int ct = 0; ct < 2; ++ct) {
      int cn = w * 32 + ct * 16 + l15;
      bfr[ct] = *(const bf16x8*)(W1t + (size_t)cn * 256 + kk * 32 + krow);
    }
    bf16x8 afr[4];
#pragma unroll
    for (int rt = 0; rt < 4; ++rt) {
      int r = rt * 16 + l15;
      int cc = kk * 32 + krow;
      afr[rt] = *(const bf16x8*)&Bt[r * 256 + (cc ^ ((r & 7) << 3))];
    }
#pragma unroll
    for (int ct = 0; ct < 2; ++ct)
#pragma unroll
      for (int rt = 0; rt < 4; ++rt)
        acc[rt][ct] = __builtin_amdgcn_mfma_f32_16x16x32_bf16(afr[rt], bfr[ct], acc[rt][ct], 0, 0, 0);
  }
#pragma unroll
  for (int ct = 0; ct < 2; ++ct) {
    int col = w * 32 + ct * 16 + l15;
    float bb = b1[col];
#pragma unroll
    for (int rt = 0; rt < 4; ++rt)
#pragma unroll
      for (int j = 0; j < 4; ++j) {
        int row = tile * 64 + rt * 16 + (lane >> 4) * 4 + j;
        if (row < N_)
          out[(size_t)row * 256 + col] = acc[rt][ct][j] + bb + x[(size_t)row * 256 + col];
      }
  }
}

// ---------------- launch ----------------

extern "C" void kernel_launch(void* const* d_in, const int* in_sizes, int n_in,
                              void* d_out, int out_size, void* d_ws, size_t ws_size,
                              hipStream_t stream) {
  const float* inps = (const float*)d_in[0];
  const int* fw = (const int*)d_in[1];
  const int* bw = (const int*)d_in[2];
  const float* Wfw = (const float*)d_in[3];
  const float* bfw = (const float*)d_in[4];
  const float* Wbw = (const float*)d_in[5];
  const float* bbw = (const float*)d_in[6];
  const float* W1 = (const float*)d_in[7];
  const float* b1 = (const float*)d_in[8];
  float* out = (float*)d_out;

  int N_ = in_sizes[0] / D_;
  int E_ = in_sizes[1] / 4;  // V * 2 * E
  int nb = (N_ + 511) >> 9;  // buckets of 512 nodes

  char* ws = (char*)d_ws;
  size_t p = 0;
  int* deg = (int*)(ws + p);              p += (size_t)4 * N_ * 4;
  int* offs = (int*)(ws + p);             p += (size_t)4 * N_ * 4;
  int* gcnt = (int*)(ws + p);             p += (size_t)4 * NBMAX * 4;
  int* csr = (int*)(ws + p);              p += (size_t)4 * E_ * 4;
  unsigned int* buckets = (unsigned int*)(ws + p);  p += (size_t)4 * NBMAX * BCAP * 4;
  unsigned short* Wt = (unsigned short*)(ws + p);   p += (size_t)4 * D_ * DH_ * 2;
  unsigned short* W1t = (unsigned short*)(ws + p);  p += (size_t)D_ * D_ * 2;
  unsigned char* y = (unsigned char*)(ws + p);      p += (size_t)4 * N_ * DH_;
  unsigned short* accb = (unsigned short*)(ws + p); p += (size_t)N_ * D_ * 2;

  prepw_k<<<768, 256, 0, stream>>>(Wfw, Wbw, W1, Wt, W1t, gcnt);

  int ntiles64 = (N_ + 63) / 64;
  ygemm_k<<<ntiles64, 512, 0, stream>>>(inps, Wt, y, N_);

  dim3 pgrid((E_ + 8191) / 8192, 4);
  part_k<<<pgrid, 512, 0, stream>>>(fw, bw, gcnt, buckets, E_, nb);
  dim3 cgrid(nb, 4);
  csr_k<<<cgrid, 512, 0, stream>>>(buckets, gcnt, deg, offs, csr, N_, E_);

  int ntiles32 = (N_ + 31) / 32;
  dim3 ggrid(ntiles32, 2);
  gnn2_k<<<ggrid, 256, 0, stream>>>(y, deg, offs, csr, bfw, bbw, accb, N_, E_);
  gemm2_k<<<ntiles64, 512, 0, stream>>>(accb, W1t, b1, inps, out, N_);
}

// Round 13
// 218.104 us; speedup vs baseline: 1.0053x; 1.0053x over previous
//
#include <hip/hip_runtime.h>

#define D_ 256
#define DH_ 128
#define NBMAX 128
#define BCAP 9216

using bf16x8 = __attribute__((ext_vector_type(8))) short;
using f32x4  = __attribute__((ext_vector_type(4))) float;
using f32x2  = __attribute__((ext_vector_type(2))) float;

__device__ __forceinline__ unsigned short f2bf(float f) {
  unsigned int u = __builtin_bit_cast(unsigned int, f);
  u += 0x7fffu + ((u >> 16) & 1u);
  return (unsigned short)(u >> 16);
}
__device__ __forceinline__ unsigned char f2fp8(float f) {
  unsigned int pk = __builtin_amdgcn_cvt_pk_fp8_f32(f, 0.f, 0u, false);
  return (unsigned char)(pk & 0xffu);
}

// ---------------- bucketed CSR build ----------------
// Edges pack into u32 (src | dst<<16) since N < 65536. Buckets of 512 dst nodes.
// part_k: per-wave histograms + int4-vectorized edge loads (16 edges/thread).

__global__ __launch_bounds__(512) void part_k(const int* __restrict__ fw,
                                              const int* __restrict__ bw,
                                              int* __restrict__ gcnt,
                                              unsigned int* __restrict__ buckets,
                                              int E_, int nb) {
  __shared__ int hist[8][NBMAX];   // per-wave histograms (4 KiB)
  int g = blockIdx.y;
  const int* src = (g < 2 ? fw : bw) + (size_t)(g & 1) * 2 * E_;
  const int* dst = src + E_;
  int t = threadIdx.x, w = t >> 6;
  for (int i = t; i < 8 * NBMAX; i += 512) ((int*)hist)[i] = 0;
  __syncthreads();
  int base = blockIdx.x * 8192 + t * 16;   // 16 contiguous edges per thread
  unsigned int pk[16];
  int lp[16];
  if (base + 16 <= E_) {
#pragma unroll
    for (int q = 0; q < 4; ++q) {
      int4 sv = *(const int4*)(src + base + q * 4);
      int4 dv = *(const int4*)(dst + base + q * 4);
      int ss[4] = {sv.x, sv.y, sv.z, sv.w};
      int dd[4] = {dv.x, dv.y, dv.z, dv.w};
#pragma unroll
      for (int r = 0; r < 4; ++r) {
        int j = q * 4 + r;
        pk[j] = (unsigned int)ss[r] | ((unsigned int)dd[r] << 16);
        lp[j] = atomicAdd(&hist[w][dd[r] >> 9], 1);
      }
    }
  } else {
#pragma unroll
    for (int j = 0; j < 16; ++j) {
      int e = base + j;
      if (e < E_) {
        int s = src[e], d = dst[e];
        pk[j] = (unsigned int)s | ((unsigned int)d << 16);
        lp[j] = atomicAdd(&hist[w][d >> 9], 1);
      } else {
        pk[j] = 0u; lp[j] = -1;
      }
    }
  }
  __syncthreads();
  // per-bucket: reserve global range once, convert per-wave hist into running bases
  if (t < nb) {
    int tot = 0;
#pragma unroll
    for (int ww = 0; ww < 8; ++ww) tot += hist[ww][t];
    int gb = atomicAdd(&gcnt[g * NBMAX + t], tot);
    int run = gb;
#pragma unroll
    for (int ww = 0; ww < 8; ++ww) { int h = hist[ww][t]; hist[ww][t] = run; run += h; }
  }
  __syncthreads();
#pragma unroll
  for (int j = 0; j < 16; ++j) {
    if (lp[j] >= 0) {
      int b = pk[j] >> 25;  // dst >> 9
      int pos = hist[w][b] + lp[j];
      if (pos < BCAP) buckets[((size_t)(g * NBMAX + b)) * BCAP + pos] = pk[j];
    }
  }
}

__global__ __launch_bounds__(512) void csr_k(const unsigned int* __restrict__ buckets,
                                             const int* __restrict__ gcnt,
                                             int* __restrict__ deg, int* __restrict__ offs,
                                             int* __restrict__ csr, int N_, int E_) {
  __shared__ int ldeg[512];
  __shared__ int loff[512];
  __shared__ int wsum[8];
  __shared__ int red[8];
  int g = blockIdx.y, b = blockIdx.x;
  int t = threadIdx.x;
  int lane = t & 63, w = t >> 6;
  int cnt = min(gcnt[g * NBMAX + b], BCAP);
  const unsigned int* ebuf = buckets + ((size_t)(g * NBMAX + b)) * BCAP;
  int nodebase = b << 9;
  int nloc = min(512, N_ - nodebase);
  ldeg[t] = 0;
  // inline bucket-base prefix: gb = sum_{j<b} min(gcnt[g][j], BCAP)
  int val = (t < b) ? min(gcnt[g * NBMAX + t], BCAP) : 0;
  for (int o = 1; o < 64; o <<= 1) val += __shfl_xor(val, o, 64);
  if (lane == 0) red[w] = val;
  __syncthreads();
  int gb = 0;
#pragma unroll
  for (int k = 0; k < 8; ++k) gb += red[k];
  for (int i = t; i < cnt; i += 512) atomicAdd(&ldeg[(ebuf[i] >> 16) & 511], 1);
  __syncthreads();
  // exclusive scan of 512 counts: 8 waves x 64 (1/lane)
  int a0 = ldeg[t];
  int incl = a0;
  for (int o = 1; o < 64; o <<= 1) {
    int x = __shfl_up(incl, o, 64);
    if (lane >= o) incl += x;
  }
  if (lane == 63) wsum[w] = incl;
  __syncthreads();
  int wpre = 0;
  for (int k = 0; k < w; ++k) wpre += wsum[k];
  loff[t] = wpre + incl - a0;
  __syncthreads();
  if (t < nloc) {
    deg[(size_t)g * N_ + nodebase + t] = ldeg[t];
    offs[(size_t)g * N_ + nodebase + t] = gb + loff[t];
  }
  ldeg[t] = 0;
  __syncthreads();
  int* csrg = csr + (size_t)g * E_ + gb;
  for (int i = t; i < cnt; i += 512) {
    unsigned int pk = ebuf[i];
    int d = (pk >> 16) & 511;
    int lp = atomicAdd(&ldeg[d], 1);
    csrg[loff[d] + lp] = (int)(pk & 0xffffu);
  }
}

// ---------------- weight prep: transposed bf16 weights (+ gcnt zeroing) ----------------

__global__ void prepw_k(const float* __restrict__ Wfw, const float* __restrict__ Wbw,
                        const float* __restrict__ W1,
                        unsigned short* __restrict__ Wt, unsigned short* __restrict__ W1t,
                        int* __restrict__ gcnt) {
  int i = blockIdx.x * blockDim.x + threadIdx.x;
  if (i < 4 * NBMAX) gcnt[i] = 0;
  const int nw = 4 * D_ * DH_;  // 131072
  if (i < nw) {
    int g = i >> 15;
    int r = i & 32767;
    int n = r >> 8, k = r & 255; // Wt[g][n][k] (DHxD, k contiguous)
    const float* W = (g < 2 ? Wfw : Wbw) + (size_t)(g & 1) * D_ * DH_;
    Wt[i] = f2bf(W[k * DH_ + n]);
  } else if (i < nw + D_ * D_) {
    int r = i - nw;
    int c = r >> 8, k = r & 255; // W1t[c][k]
    W1t[r] = f2bf(W1[k * D_ + c]);
  }
}

// ---------------- y_g = x @ W_g, 64-row tiles, 8 waves (wave -> graph/col-half) ----------------

__global__ __launch_bounds__(512, 4) void ygemm_k(const float* __restrict__ x,
                                                  const unsigned short* __restrict__ Wt,
                                                  unsigned char* __restrict__ y, int N_) {
  __shared__ unsigned short At[64 * 256];  // 32 KiB XOR-swizzled bf16 tile of x
  int t = threadIdx.x, lane = t & 63, w = t >> 6;
  int tile = blockIdx.x;
#pragma unroll
  for (int it = 0; it < 8; ++it) {
    int idx = it * 512 + t;          // 4096 float4 slots = 64 rows x 64
    int row = idx >> 6, slot = idx & 63;
    int gr = tile * 64 + row;
    float4 v = {0.f, 0.f, 0.f, 0.f};
    if (gr < N_) v = ((const float4*)x)[(size_t)gr * 64 + slot];
    int c = slot * 4;
    int sc2 = (c & 7) | ((((c >> 3)) ^ (row & 7)) << 3);
    ushort4 o;
    o.x = f2bf(v.x); o.y = f2bf(v.y); o.z = f2bf(v.z); o.w = f2bf(v.w);
    *(ushort4*)&At[row * 256 + sc2] = o;
  }
  __syncthreads();
  int krow = (lane >> 4) * 8;
  int l15 = lane & 15;
  int g = w >> 1, ch = w & 1;      // wave -> (graph, column half)
  const unsigned short* Wg = Wt + (size_t)g * (DH_ * D_);
  f32x4 acc[4][4];
#pragma unroll
  for (int a = 0; a < 4; ++a)
#pragma unroll
    for (int b = 0; b < 4; ++b) acc[a][b] = (f32x4){0.f, 0.f, 0.f, 0.f};
#pragma unroll
  for (int kk = 0; kk < 8; ++kk) {
    bf16x8 bfr[4];
#pragma unroll
    for (int ct = 0; ct < 4; ++ct) {
      int n = ch * 64 + ct * 16 + l15;
      bfr[ct] = *(const bf16x8*)(Wg + (size_t)n * 256 + kk * 32 + krow);
    }
    bf16x8 afr[4];
#pragma unroll
    for (int rt = 0; rt < 4; ++rt) {
      int r = rt * 16 + l15;
      int cc = kk * 32 + krow;
      afr[rt] = *(const bf16x8*)&At[r * 256 + (cc ^ ((r & 7) << 3))];
    }
#pragma unroll
    for (int ct = 0; ct < 4; ++ct)
#pragma unroll
      for (int rt = 0; rt < 4; ++rt)
        acc[rt][ct] = __builtin_amdgcn_mfma_f32_16x16x32_bf16(afr[rt], bfr[ct], acc[rt][ct], 0, 0, 0);
  }
  unsigned char* yg = y + (size_t)g * N_ * DH_;
#pragma unroll
  for (int rt = 0; rt < 4; ++rt)
#pragma unroll
    for (int j = 0; j < 4; ++j) {
      int row = tile * 64 + rt * 16 + (lane >> 4) * 4 + j;
      if (row < N_) {
#pragma unroll
        for (int ct = 0; ct < 4; ++ct)
          yg[(size_t)row * DH_ + ch * 64 + ct * 16 + l15] = f2fp8(acc[rt][ct][j]);
      }
    }
}

// ---------------- gather: 16-lane group per row, 8-deep unrolled, no cross-lane reduce ----------------

__device__ __forceinline__ void acc2(f32x2* s, uint2 q) {
  s[0] += __builtin_amdgcn_cvt_pk_f32_fp8(q.x, false);
  s[1] += __builtin_amdgcn_cvt_pk_f32_fp8(q.x, true);
  s[2] += __builtin_amdgcn_cvt_pk_f32_fp8(q.y, false);
  s[3] += __builtin_amdgcn_cvt_pk_f32_fp8(q.y, true);
}

#define ROWQ(idx) (*(const uint2*)(yg + ((((unsigned)(idx) & 0xffffu) << 7) + boff)))

#define GATHER(sacc, dgv, offv, gidx)                                                   \
  {                                                                                     \
    const int* lst = csr + (size_t)(gidx) * E_ + (offv);                                \
    const unsigned char* yg = y + (size_t)(gidx) * N_ * DH_;                            \
    int j = 0;                                                                          \
    int jend8 = (dgv) & ~7;                                                             \
    _Pragma("unroll 1")                                                                 \
    for (; j < jend8; j += 8) {                                                         \
      int4 iva = *(const int4*)(lst + j);                                               \
      int4 ivb = *(const int4*)(lst + j + 4);                                           \
      uint2 q0 = ROWQ(iva.x); uint2 q1 = ROWQ(iva.y);                                   \
      uint2 q2 = ROWQ(iva.z); uint2 q3 = ROWQ(iva.w);                                   \
      uint2 q4 = ROWQ(ivb.x); uint2 q5 = ROWQ(ivb.y);                                   \
      uint2 q6 = ROWQ(ivb.z); uint2 q7 = ROWQ(ivb.w);                                   \
      acc2(sacc, q0); acc2(sacc, q1); acc2(sacc, q2); acc2(sacc, q3);                   \
      acc2(sacc, q4); acc2(sacc, q5); acc2(sacc, q6); acc2(sacc, q7);                   \
    }                                                                                   \
    if (j + 4 <= (dgv)) {                                                               \
      int4 iv = *(const int4*)(lst + j);                                                \
      uint2 q0 = ROWQ(iv.x); uint2 q1 = ROWQ(iv.y);                                     \
      uint2 q2 = ROWQ(iv.z); uint2 q3 = ROWQ(iv.w);                                     \
      acc2(sacc, q0); acc2(sacc, q1); acc2(sacc, q2); acc2(sacc, q3);                   \
      j += 4;                                                                           \
    }                                                                                   \
    if (j < (dgv)) {                                                                    \
      int4 iv = *(const int4*)(lst + j);                                                \
      uint2 q0 = ROWQ(iv.x); uint2 q1 = ROWQ(iv.y); uint2 q2 = ROWQ(iv.z);              \
      if (j + 0 < (dgv)) acc2(sacc, q0);                                                \
      if (j + 1 < (dgv)) acc2(sacc, q1);                                                \
      if (j + 2 < (dgv)) acc2(sacc, q2);                                                \
    }                                                                                   \
  }

__global__ __launch_bounds__(256, 6) void gnn2_k(
    const unsigned char* __restrict__ y,
    const int* __restrict__ deg, const int* __restrict__ offs, const int* __restrict__ csr,
    const float* __restrict__ bias_fw, const float* __restrict__ bias_bw,
    unsigned short* __restrict__ accb, int N_, int E_) {
  const int tid = threadIdx.x;
  const int lane = tid & 63, w = tid >> 6;
  const int grp = lane >> 4, l15 = lane & 15;
  const int tile = blockIdx.x, dir = blockIdx.y;  // 0 = fw, 1 = bw
  const int colbase = dir ? 0 : 128;              // concat([bw, fw])
  const float* bias = dir ? bias_bw : bias_fw;
  const unsigned boff = l15 * 8;  // byte (and element) offset within the 128-B fp8 row
  const int g0 = dir * 2, g1 = g0 + 1;

#pragma unroll 1
  for (int rr = 0; rr < 2; ++rr) {
    int nd = tile * 32 + rr * 16 + w * 4 + grp;   // this group's row
    bool act = nd < N_;
    int nds = act ? nd : 0;
    f32x2 s0[4], s1[4];
#pragma unroll
    for (int k = 0; k < 4; ++k) { s0[k] = (f32x2){0.f, 0.f}; s1[k] = (f32x2){0.f, 0.f}; }
    int dg0 = deg[(size_t)g0 * N_ + nds];
    int off0 = offs[(size_t)g0 * N_ + nds];
    int dg1 = deg[(size_t)g1 * N_ + nds];
    int off1 = offs[(size_t)g1 * N_ + nds];
    if (!act) { dg0 = 0; dg1 = 0; }

    GATHER(s0, dg0, off0, g0);
    GATHER(s1, dg1, off1, g1);

    float sc0 = 1.0f / (float)max(dg0, 1);
    float sc1 = 1.0f / (float)max(dg1, 1);
    const float* bp0 = bias + boff;
    const float* bp1 = bias + DH_ + boff;
    uint4 pk;
    unsigned* pw = (unsigned*)&pk;
#pragma unroll
    for (int k = 0; k < 4; ++k) {
      float h0 = fmaxf(s0[k].x * sc0 + bp0[2 * k],     0.f) + fmaxf(s1[k].x * sc1 + bp1[2 * k],     0.f);
      float h1 = fmaxf(s0[k].y * sc0 + bp0[2 * k + 1], 0.f) + fmaxf(s1[k].y * sc1 + bp1[2 * k + 1], 0.f);
      pw[k] = (unsigned)f2bf(h0) | ((unsigned)f2bf(h1) << 16);
    }
    if (act) *(uint4*)(accb + (size_t)nd * 256 + colbase + boff) = pk;
  }
}

// ---------------- GEMM2: out = accb @ W1 + b1 + inps (64-row tiles, 8 waves) ----------------

__global__ __launch_bounds__(512, 4) void gemm2_k(
    const unsigned short* __restrict__ accb, const unsigned short* __restrict__ W1t,
    const float* __restrict__ b1, const float* __restrict__ x,
    float* __restrict__ out, int N_) {
  __shared__ unsigned short Bt[64 * 256];  // 32 KiB XOR-swizzled accb tile
  int tid = threadIdx.x;
  int lane = tid & 63, w = tid >> 6;
  int l15 = lane & 15;
  int tile = blockIdx.x;
  // stage: 2048 x 16B slots, coalesced (32 consecutive slots per row)
#pragma unroll
  for (int it = 0; it < 4; ++it) {
    int idx = it * 512 + tid;
    int row = idx >> 5, slot = idx & 31;
    int gr = min(tile * 64 + row, N_ - 1);
    uint4 v = *(const uint4*)(accb + (size_t)gr * 256 + slot * 8);
    int c = slot * 8;
    *(uint4*)&Bt[row * 256 + (c ^ ((row & 7) << 3))] = v;
  }
  __syncthreads();
  f32x4 acc[4][2];
#pragma unroll
  for (int a = 0; a < 4; ++a)
#pragma unroll
    for (int b = 0; b < 2; ++b) acc[a][b] = (f32x4){0.f, 0.f, 0.f, 0.f};
  int krow = (lane >> 4) * 8;
#pragma unroll
  for (int kk = 0; kk < 8; ++kk) {
    bf16x8 bfr[2];
#pragma unroll
    for (int ct = 0; ct < 2; ++ct) {
      int cn = w * 32 + ct * 16 + l15;
      bfr[ct] = *(const bf16x8*)(W1t + (size_t)cn * 256 + kk * 32 + krow);
    }
    bf16x8 afr[4];
#pragma unroll
    for (int rt = 0; rt < 4; ++rt) {
      int r = rt * 16 + l15;
      int cc = kk * 32 + krow;
      afr[rt] = *(const bf16x8*)&Bt[r * 256 + (cc ^ ((r & 7) << 3))];
    }
#pragma unroll
    for (int ct = 0; ct < 2; ++ct)
#pragma unroll
      for (int rt = 0; rt < 4; ++rt)
        acc[rt][ct] = __builtin_amdgcn_mfma_f32_16x16x32_bf16(afr[rt], bfr[ct], acc[rt][ct], 0, 0, 0);
  }
#pragma unroll
  for (int ct = 0; ct < 2; ++ct) {
    int col = w * 32 + ct * 16 + l15;
    float bb = b1[col];
#pragma unroll
    for (int rt = 0; rt < 4; ++rt)
#pragma unroll
      for (int j = 0; j < 4; ++j) {
        int row = tile * 64 + rt * 16 + (lane >> 4) * 4 + j;
        if (row < N_)
          out[(size_t)row * 256 + col] = acc[rt][ct][j] + bb + x[(size_t)row * 256 + col];
      }
  }
}

// ---------------- launch ----------------

extern "C" void kernel_launch(void* const* d_in, const int* in_sizes, int n_in,
                              void* d_out, int out_size, void* d_ws, size_t ws_size,
                              hipStream_t stream) {
  const float* inps = (const float*)d_in[0];
  const int* fw = (const int*)d_in[1];
  const int* bw = (const int*)d_in[2];
  const float* Wfw = (const float*)d_in[3];
  const float* bfw = (const float*)d_in[4];
  const float* Wbw = (const float*)d_in[5];
  const float* bbw = (const float*)d_in[6];
  const float* W1 = (const float*)d_in[7];
  const float* b1 = (const float*)d_in[8];
  float* out = (float*)d_out;

  int N_ = in_sizes[0] / D_;
  int E_ = in_sizes[1] / 4;  // V * 2 * E
  int nb = (N_ + 511) >> 9;  // buckets of 512 nodes

  char* ws = (char*)d_ws;
  size_t p = 0;
  int* deg = (int*)(ws + p);              p += (size_t)4 * N_ * 4;
  int* offs = (int*)(ws + p);             p += (size_t)4 * N_ * 4;
  int* gcnt = (int*)(ws + p);             p += (size_t)4 * NBMAX * 4;
  int* csr = (int*)(ws + p);              p += (size_t)4 * E_ * 4;
  unsigned int* buckets = (unsigned int*)(ws + p);  p += (size_t)4 * NBMAX * BCAP * 4;
  unsigned short* Wt = (unsigned short*)(ws + p);   p += (size_t)4 * D_ * DH_ * 2;
  unsigned short* W1t = (unsigned short*)(ws + p);  p += (size_t)D_ * D_ * 2;
  unsigned char* y = (unsigned char*)(ws + p);      p += (size_t)4 * N_ * DH_;
  unsigned short* accb = (unsigned short*)(ws + p); p += (size_t)N_ * D_ * 2;

  prepw_k<<<768, 256, 0, stream>>>(Wfw, Wbw, W1, Wt, W1t, gcnt);

  int ntiles64 = (N_ + 63) / 64;
  ygemm_k<<<ntiles64, 512, 0, stream>>>(inps, Wt, y, N_);

  dim3 pgrid((E_ + 8191) / 8192, 4);
  part_k<<<pgrid, 512, 0, stream>>>(fw, bw, gcnt, buckets, E_, nb);
  dim3 cgrid(nb, 4);
  csr_k<<<cgrid, 512, 0, stream>>>(buckets, gcnt, deg, offs, csr, N_, E_);

  int ntiles32 = (N_ + 31) / 32;
  dim3 ggrid(ntiles32, 2);
  gnn2_k<<<ggrid, 256, 0, stream>>>(y, deg, offs, csr, bfw, bbw, accb, N_, E_);
  gemm2_k<<<ntiles64, 512, 0, stream>>>(accb, W1t, b1, inps, out, N_);
}

// Round 14
// 207.230 us; speedup vs baseline: 1.0581x; 1.0525x over previous
//
#include <hip/hip_runtime.h>

#define D_ 256
#define DH_ 128
#define NBMAX 128
#define BCAP 9216

using bf16x8 = __attribute__((ext_vector_type(8))) short;
using f32x4  = __attribute__((ext_vector_type(4))) float;
using f32x2  = __attribute__((ext_vector_type(2))) float;

__device__ __forceinline__ unsigned short f2bf(float f) {
  unsigned int u = __builtin_bit_cast(unsigned int, f);
  u += 0x7fffu + ((u >> 16) & 1u);
  return (unsigned short)(u >> 16);
}
__device__ __forceinline__ unsigned char f2fp8(float f) {
  unsigned int pk = __builtin_amdgcn_cvt_pk_fp8_f32(f, 0.f, 0u, false);
  return (unsigned char)(pk & 0xffu);
}

// ---------------- bucketed CSR build ----------------
// Edges pack into u32 (src | dst<<16) since N < 65536. Buckets of 512 dst nodes.
// part_k: per-wave histograms + int4-vectorized edge loads (16 edges/thread).

__global__ __launch_bounds__(512) void part_k(const int* __restrict__ fw,
                                              const int* __restrict__ bw,
                                              int* __restrict__ gcnt,
                                              unsigned int* __restrict__ buckets,
                                              int E_, int nb) {
  __shared__ int hist[8][NBMAX];   // per-wave histograms (4 KiB)
  int g = blockIdx.y;
  const int* src = (g < 2 ? fw : bw) + (size_t)(g & 1) * 2 * E_;
  const int* dst = src + E_;
  int t = threadIdx.x, w = t >> 6;
  for (int i = t; i < 8 * NBMAX; i += 512) ((int*)hist)[i] = 0;
  __syncthreads();
  int base = blockIdx.x * 8192 + t * 16;   // 16 contiguous edges per thread
  unsigned int pk[16];
  int lp[16];
  if (base + 16 <= E_) {
#pragma unroll
    for (int q = 0; q < 4; ++q) {
      int4 sv = *(const int4*)(src + base + q * 4);
      int4 dv = *(const int4*)(dst + base + q * 4);
      int ss[4] = {sv.x, sv.y, sv.z, sv.w};
      int dd[4] = {dv.x, dv.y, dv.z, dv.w};
#pragma unroll
      for (int r = 0; r < 4; ++r) {
        int j = q * 4 + r;
        pk[j] = (unsigned int)ss[r] | ((unsigned int)dd[r] << 16);
        lp[j] = atomicAdd(&hist[w][dd[r] >> 9], 1);
      }
    }
  } else {
#pragma unroll
    for (int j = 0; j < 16; ++j) {
      int e = base + j;
      if (e < E_) {
        int s = src[e], d = dst[e];
        pk[j] = (unsigned int)s | ((unsigned int)d << 16);
        lp[j] = atomicAdd(&hist[w][d >> 9], 1);
      } else {
        pk[j] = 0u; lp[j] = -1;
      }
    }
  }
  __syncthreads();
  // per-bucket: reserve global range once, convert per-wave hist into running bases
  if (t < nb) {
    int tot = 0;
#pragma unroll
    for (int ww = 0; ww < 8; ++ww) tot += hist[ww][t];
    int gb = atomicAdd(&gcnt[g * NBMAX + t], tot);
    int run = gb;
#pragma unroll
    for (int ww = 0; ww < 8; ++ww) { int h = hist[ww][t]; hist[ww][t] = run; run += h; }
  }
  __syncthreads();
#pragma unroll
  for (int j = 0; j < 16; ++j) {
    if (lp[j] >= 0) {
      int b = pk[j] >> 25;  // dst >> 9
      int pos = hist[w][b] + lp[j];
      if (pos < BCAP) buckets[((size_t)(g * NBMAX + b)) * BCAP + pos] = pk[j];
    }
  }
}

__global__ __launch_bounds__(512) void csr_k(const unsigned int* __restrict__ buckets,
                                             const int* __restrict__ gcnt,
                                             int* __restrict__ deg, int* __restrict__ offs,
                                             int* __restrict__ csr, int N_, int E_) {
  __shared__ int ldeg[512];
  __shared__ int loff[512];
  __shared__ int wsum[8];
  __shared__ int red[8];
  int g = blockIdx.y, b = blockIdx.x;
  int t = threadIdx.x;
  int lane = t & 63, w = t >> 6;
  int cnt = min(gcnt[g * NBMAX + b], BCAP);
  const unsigned int* ebuf = buckets + ((size_t)(g * NBMAX + b)) * BCAP;
  int nodebase = b << 9;
  int nloc = min(512, N_ - nodebase);
  ldeg[t] = 0;
  // inline bucket-base prefix: gb = sum_{j<b} min(gcnt[g][j], BCAP)
  int val = (t < b) ? min(gcnt[g * NBMAX + t], BCAP) : 0;
  for (int o = 1; o < 64; o <<= 1) val += __shfl_xor(val, o, 64);
  if (lane == 0) red[w] = val;
  __syncthreads();
  int gb = 0;
#pragma unroll
  for (int k = 0; k < 8; ++k) gb += red[k];
  for (int i = t; i < cnt; i += 512) atomicAdd(&ldeg[(ebuf[i] >> 16) & 511], 1);
  __syncthreads();
  // exclusive scan of 512 counts: 8 waves x 64 (1/lane)
  int a0 = ldeg[t];
  int incl = a0;
  for (int o = 1; o < 64; o <<= 1) {
    int x = __shfl_up(incl, o, 64);
    if (lane >= o) incl += x;
  }
  if (lane == 63) wsum[w] = incl;
  __syncthreads();
  int wpre = 0;
  for (int k = 0; k < w; ++k) wpre += wsum[k];
  loff[t] = wpre + incl - a0;
  __syncthreads();
  if (t < nloc) {
    deg[(size_t)g * N_ + nodebase + t] = ldeg[t];
    offs[(size_t)g * N_ + nodebase + t] = gb + loff[t];
  }
  ldeg[t] = 0;
  __syncthreads();
  int* csrg = csr + (size_t)g * E_ + gb;
  for (int i = t; i < cnt; i += 512) {
    unsigned int pk = ebuf[i];
    int d = (pk >> 16) & 511;
    int lp = atomicAdd(&ldeg[d], 1);
    csrg[loff[d] + lp] = (int)(pk & 0xffffu);
  }
}

// ---------------- weight prep: transposed bf16 weights (+ gcnt zeroing) ----------------

__global__ void prepw_k(const float* __restrict__ Wfw, const float* __restrict__ Wbw,
                        const float* __restrict__ W1,
                        unsigned short* __restrict__ Wt, unsigned short* __restrict__ W1t,
                        int* __restrict__ gcnt) {
  int i = blockIdx.x * blockDim.x + threadIdx.x;
  if (i < 4 * NBMAX) gcnt[i] = 0;
  const int nw = 4 * D_ * DH_;  // 131072
  if (i < nw) {
    int g = i >> 15;
    int r = i & 32767;
    int n = r >> 8, k = r & 255; // Wt[g][n][k] (DHxD, k contiguous)
    const float* W = (g < 2 ? Wfw : Wbw) + (size_t)(g & 1) * D_ * DH_;
    Wt[i] = f2bf(W[k * DH_ + n]);
  } else if (i < nw + D_ * D_) {
    int r = i - nw;
    int c = r >> 8, k = r & 255; // W1t[c][k]
    W1t[r] = f2bf(W1[k * D_ + c]);
  }
}

// ---------------- y_g = x @ W_g, 64-row tiles, 8 waves (wave -> graph/col-half) ----------------

__global__ __launch_bounds__(512, 4) void ygemm_k(const float* __restrict__ x,
                                                  const unsigned short* __restrict__ Wt,
                                                  unsigned char* __restrict__ y, int N_) {
  __shared__ unsigned short At[64 * 256];  // 32 KiB XOR-swizzled bf16 tile of x
  int t = threadIdx.x, lane = t & 63, w = t >> 6;
  int tile = blockIdx.x;
#pragma unroll
  for (int it = 0; it < 8; ++it) {
    int idx = it * 512 + t;          // 4096 float4 slots = 64 rows x 64
    int row = idx >> 6, slot = idx & 63;
    int gr = tile * 64 + row;
    float4 v = {0.f, 0.f, 0.f, 0.f};
    if (gr < N_) v = ((const float4*)x)[(size_t)gr * 64 + slot];
    int c = slot * 4;
    int sc2 = (c & 7) | ((((c >> 3)) ^ (row & 7)) << 3);
    ushort4 o;
    o.x = f2bf(v.x); o.y = f2bf(v.y); o.z = f2bf(v.z); o.w = f2bf(v.w);
    *(ushort4*)&At[row * 256 + sc2] = o;
  }
  __syncthreads();
  int krow = (lane >> 4) * 8;
  int l15 = lane & 15;
  int g = w >> 1, ch = w & 1;      // wave -> (graph, column half)
  const unsigned short* Wg = Wt + (size_t)g * (DH_ * D_);
  f32x4 acc[4][4];
#pragma unroll
  for (int a = 0; a < 4; ++a)
#pragma unroll
    for (int b = 0; b < 4; ++b) acc[a][b] = (f32x4){0.f, 0.f, 0.f, 0.f};
#pragma unroll
  for (int kk = 0; kk < 8; ++kk) {
    bf16x8 bfr[4];
#pragma unroll
    for (int ct = 0; ct < 4; ++ct) {
      int n = ch * 64 + ct * 16 + l15;
      bfr[ct] = *(const bf16x8*)(Wg + (size_t)n * 256 + kk * 32 + krow);
    }
    bf16x8 afr[4];
#pragma unroll
    for (int rt = 0; rt < 4; ++rt) {
      int r = rt * 16 + l15;
      int cc = kk * 32 + krow;
      afr[rt] = *(const bf16x8*)&At[r * 256 + (cc ^ ((r & 7) << 3))];
    }
#pragma unroll
    for (int ct = 0; ct < 4; ++ct)
#pragma unroll
      for (int rt = 0; rt < 4; ++rt)
        acc[rt][ct] = __builtin_amdgcn_mfma_f32_16x16x32_bf16(afr[rt], bfr[ct], acc[rt][ct], 0, 0, 0);
  }
  unsigned char* yg = y + (size_t)g * N_ * DH_;
#pragma unroll
  for (int rt = 0; rt < 4; ++rt)
#pragma unroll
    for (int j = 0; j < 4; ++j) {
      int row = tile * 64 + rt * 16 + (lane >> 4) * 4 + j;
      if (row < N_) {
#pragma unroll
        for (int ct = 0; ct < 4; ++ct)
          yg[(size_t)row * DH_ + ch * 64 + ct * 16 + l15] = f2fp8(acc[rt][ct][j]);
      }
    }
}

// ---------------- gather: 16-lane group per row, no cross-lane reduction ----------------

__device__ __forceinline__ void acc2(f32x2* s, uint2 q) {
  s[0] += __builtin_amdgcn_cvt_pk_f32_fp8(q.x, false);
  s[1] += __builtin_amdgcn_cvt_pk_f32_fp8(q.x, true);
  s[2] += __builtin_amdgcn_cvt_pk_f32_fp8(q.y, false);
  s[3] += __builtin_amdgcn_cvt_pk_f32_fp8(q.y, true);
}

#define GATHER(sacc, dgv, offv, gidx)                                                   \
  {                                                                                     \
    const int* lst = csr + (size_t)(gidx) * E_ + (offv);                                \
    const unsigned char* yg = y + (size_t)(gidx) * N_ * DH_;                            \
    int jend = (dgv) & ~3;                                                              \
    int j = 0;                                                                          \
    _Pragma("unroll 1")                                                                 \
    for (; j < jend; j += 4) {                                                          \
      int4 iv = *(const int4*)(lst + j);                                                \
      uint2 q0 = *(const uint2*)(yg + ((((unsigned)iv.x & 0xffffu) << 7) + boff));      \
      uint2 q1 = *(const uint2*)(yg + ((((unsigned)iv.y & 0xffffu) << 7) + boff));      \
      uint2 q2 = *(const uint2*)(yg + ((((unsigned)iv.z & 0xffffu) << 7) + boff));      \
      uint2 q3 = *(const uint2*)(yg + ((((unsigned)iv.w & 0xffffu) << 7) + boff));      \
      acc2(sacc, q0); acc2(sacc, q1); acc2(sacc, q2); acc2(sacc, q3);                   \
    }                                                                                   \
    if (j < (dgv)) {                                                                    \
      int4 iv = *(const int4*)(lst + j);                                                \
      uint2 q0 = *(const uint2*)(yg + ((((unsigned)iv.x & 0xffffu) << 7) + boff));      \
      uint2 q1 = *(const uint2*)(yg + ((((unsigned)iv.y & 0xffffu) << 7) + boff));      \
      uint2 q2 = *(const uint2*)(yg + ((((unsigned)iv.z & 0xffffu) << 7) + boff));      \
      if (j + 0 < (dgv)) acc2(sacc, q0);                                                \
      if (j + 1 < (dgv)) acc2(sacc, q1);                                                \
      if (j + 2 < (dgv)) acc2(sacc, q2);                                                \
    }                                                                                   \
  }

__global__ __launch_bounds__(256, 6) void gnn2_k(
    const unsigned char* __restrict__ y,
    const int* __restrict__ deg, const int* __restrict__ offs, const int* __restrict__ csr,
    const float* __restrict__ bias_fw, const float* __restrict__ bias_bw,
    unsigned short* __restrict__ accb, int N_, int E_) {
  const int tid = threadIdx.x;
  const int lane = tid & 63, w = tid >> 6;
  const int grp = lane >> 4, l15 = lane & 15;
  const int tile = blockIdx.x, dir = blockIdx.y;  // 0 = fw, 1 = bw
  const int colbase = dir ? 0 : 128;              // concat([bw, fw])
  const float* bias = dir ? bias_bw : bias_fw;
  const unsigned boff = l15 * 8;  // byte (and element) offset within the 128-B fp8 row
  const int g0 = dir * 2, g1 = g0 + 1;

#pragma unroll 1
  for (int rr = 0; rr < 2; ++rr) {
    int nd = tile * 32 + rr * 16 + w * 4 + grp;   // this group's row
    bool act = nd < N_;
    int nds = act ? nd : 0;
    f32x2 s0[4], s1[4];
#pragma unroll
    for (int k = 0; k < 4; ++k) { s0[k] = (f32x2){0.f, 0.f}; s1[k] = (f32x2){0.f, 0.f}; }
    int dg0 = deg[(size_t)g0 * N_ + nds];
    int off0 = offs[(size_t)g0 * N_ + nds];
    int dg1 = deg[(size_t)g1 * N_ + nds];
    int off1 = offs[(size_t)g1 * N_ + nds];
    if (!act) { dg0 = 0; dg1 = 0; }

    GATHER(s0, dg0, off0, g0);
    GATHER(s1, dg1, off1, g1);

    float sc0 = 1.0f / (float)max(dg0, 1);
    float sc1 = 1.0f / (float)max(dg1, 1);
    const float* bp0 = bias + boff;
    const float* bp1 = bias + DH_ + boff;
    uint4 pk;
    unsigned* pw = (unsigned*)&pk;
#pragma unroll
    for (int k = 0; k < 4; ++k) {
      float h0 = fmaxf(s0[k].x * sc0 + bp0[2 * k],     0.f) + fmaxf(s1[k].x * sc1 + bp1[2 * k],     0.f);
      float h1 = fmaxf(s0[k].y * sc0 + bp0[2 * k + 1], 0.f) + fmaxf(s1[k].y * sc1 + bp1[2 * k + 1], 0.f);
      pw[k] = (unsigned)f2bf(h0) | ((unsigned)f2bf(h1) << 16);
    }
    if (act) *(uint4*)(accb + (size_t)nd * 256 + colbase + boff) = pk;
  }
}

// ---------------- GEMM2: out = accb @ W1 + b1 + inps (64-row tiles, 8 waves) ----------------

__global__ __launch_bounds__(512, 4) void gemm2_k(
    const unsigned short* __restrict__ accb, const unsigned short* __restrict__ W1t,
    const float* __restrict__ b1, const float* __restrict__ x,
    float* __restrict__ out, int N_) {
  __shared__ unsigned short Bt[64 * 256];  // 32 KiB XOR-swizzled accb tile
  int tid = threadIdx.x;
  int lane = tid & 63, w = tid >> 6;
  int l15 = lane & 15;
  int tile = blockIdx.x;
  // stage: 2048 x 16B slots, coalesced (32 consecutive slots per row)
#pragma unroll
  for (int it = 0; it < 4; ++it) {
    int idx = it * 512 + tid;
    int row = idx >> 5, slot = idx & 31;
    int gr = min(tile * 64 + row, N_ - 1);
    uint4 v = *(const uint4*)(accb + (size_t)gr * 256 + slot * 8);
    int c = slot * 8;
    *(uint4*)&Bt[row * 256 + (c ^ ((row & 7) << 3))] = v;
  }
  __syncthreads();
  f32x4 acc[4][2];
#pragma unroll
  for (int a = 0; a < 4; ++a)
#pragma unroll
    for (int b = 0; b < 2; ++b) acc[a][b] = (f32x4){0.f, 0.f, 0.f, 0.f};
  int krow = (lane >> 4) * 8;
#pragma unroll
  for (int kk = 0; kk < 8; ++kk) {
    bf16x8 bfr[2];
#pragma unroll
    for (int ct = 0; ct < 2; ++ct) {
      int cn = w * 32 + ct * 16 + l15;
      bfr[ct] = *(const bf16x8*)(W1t + (size_t)cn * 256 + kk * 32 + krow);
    }
    bf16x8 afr[4];
#pragma unroll
    for (int rt = 0; rt < 4; ++rt) {
      int r = rt * 16 + l15;
      int cc = kk * 32 + krow;
      afr[rt] = *(const bf16x8*)&Bt[r * 256 + (cc ^ ((r & 7) << 3))];
    }
#pragma unroll
    for (int ct = 0; ct < 2; ++ct)
#pragma unroll
      for (int rt = 0; rt < 4; ++rt)
        acc[rt][ct] = __builtin_amdgcn_mfma_f32_16x16x32_bf16(afr[rt], bfr[ct], acc[rt][ct], 0, 0, 0);
  }
#pragma unroll
  for (int ct = 0; ct < 2; ++ct) {
    int col = w * 32 + ct * 16 + l15;
    float bb = b1[col];
#pragma unroll
    for (int rt = 0; rt < 4; ++rt)
#pragma unroll
      for (int j = 0; j < 4; ++j) {
        int row = tile * 64 + rt * 16 + (lane >> 4) * 4 + j;
        if (row < N_)
          out[(size_t)row * 256 + col] = acc[rt][ct][j] + bb + x[(size_t)row * 256 + col];
      }
  }
}

// ---------------- launch ----------------

extern "C" void kernel_launch(void* const* d_in, const int* in_sizes, int n_in,
                              void* d_out, int out_size, void* d_ws, size_t ws_size,
                              hipStream_t stream) {
  const float* inps = (const float*)d_in[0];
  const int* fw = (const int*)d_in[1];
  const int* bw = (const int*)d_in[2];
  const float* Wfw = (const float*)d_in[3];
  const float* bfw = (const float*)d_in[4];
  const float* Wbw = (const float*)d_in[5];
  const float* bbw = (const float*)d_in[6];
  const float* W1 = (const float*)d_in[7];
  const float* b1 = (const float*)d_in[8];
  float* out = (float*)d_out;

  int N_ = in_sizes[0] / D_;
  int E_ = in_sizes[1] / 4;  // V * 2 * E
  int nb = (N_ + 511) >> 9;  // buckets of 512 nodes

  char* ws = (char*)d_ws;
  size_t p = 0;
  int* deg = (int*)(ws + p);              p += (size_t)4 * N_ * 4;
  int* offs = (int*)(ws + p);             p += (size_t)4 * N_ * 4;
  int* gcnt = (int*)(ws + p);             p += (size_t)4 * NBMAX * 4;
  int* csr = (int*)(ws + p);              p += (size_t)4 * E_ * 4;
  unsigned int* buckets = (unsigned int*)(ws + p);  p += (size_t)4 * NBMAX * BCAP * 4;
  unsigned short* Wt = (unsigned short*)(ws + p);   p += (size_t)4 * D_ * DH_ * 2;
  unsigned short* W1t = (unsigned short*)(ws + p);  p += (size_t)D_ * D_ * 2;
  unsigned char* y = (unsigned char*)(ws + p);      p += (size_t)4 * N_ * DH_;
  unsigned short* accb = (unsigned short*)(ws + p); p += (size_t)N_ * D_ * 2;

  prepw_k<<<768, 256, 0, stream>>>(Wfw, Wbw, W1, Wt, W1t, gcnt);

  int ntiles64 = (N_ + 63) / 64;
  ygemm_k<<<ntiles64, 512, 0, stream>>>(inps, Wt, y, N_);

  dim3 pgrid((E_ + 8191) / 8192, 4);
  part_k<<<pgrid, 512, 0, stream>>>(fw, bw, gcnt, buckets, E_, nb);
  dim3 cgrid(nb, 4);
  csr_k<<<cgrid, 512, 0, stream>>>(buckets, gcnt, deg, offs, csr, N_, E_);

  int ntiles32 = (N_ + 31) / 32;
  dim3 ggrid(ntiles32, 2);
  gnn2_k<<<ggrid, 256, 0, stream>>>(y, deg, offs, csr, bfw, bbw, accb, N_, E_);
  gemm2_k<<<ntiles64, 512, 0, stream>>>(accb, W1t, b1, inps, out, N_);
}